// Round 1
// baseline (11490.105 us; speedup 1.0000x reference)
//
#include <hip/hip_runtime.h>
#include <cstdint>
#include <cstddef>

#define NN 100000
#define NE 1600000
#define FEAT 140
#define EMB 64
#define HID 128
#define LN_EPS 1e-5f

__device__ __forceinline__ float gelu_exact(float x) {
    return 0.5f * x * (1.0f + erff(x * 0.70710678118654752440f));
}

__device__ __forceinline__ float4 fma4(float4 w, float s, float4 acc) {
    acc.x = fmaf(s, w.x, acc.x);
    acc.y = fmaf(s, w.y, acc.y);
    acc.z = fmaf(s, w.z, acc.z);
    acc.w = fmaf(s, w.w, acc.w);
    return acc;
}

// ---------------- input projection: h = gelu(LN(concat @ W_in + b_in)) ----------------
__global__ __launch_bounds__(128) void input_proj_kernel(
    const float* __restrict__ node_feat, const float* __restrict__ topo,
    const float* __restrict__ embed, const int* __restrict__ opcode,
    const float* __restrict__ W_in, const float* __restrict__ b_in,
    const float* __restrict__ g0, const float* __restrict__ b0,
    float* __restrict__ h_out)
{
    __shared__ float x_s[16][208];   // 205 used, padded to 208 (zeros)
    const int t = threadIdx.x;
    const int node0 = blockIdx.x * 16;

    for (int m = 0; m < 16; ++m) {
        const int node = node0 + m;
        for (int c = t; c < FEAT; c += 128)
            x_s[m][c] = node_feat[(size_t)node * FEAT + c];
        if (t < EMB) {
            int op = opcode[node];
            op = min(max(op, 0), 127);
            x_s[m][FEAT + t] = embed[op * EMB + t];
        } else if (t == 64) {
            x_s[m][204] = topo[node];
        } else if (t >= 65 && t < 68) {
            x_s[m][140 + t] = 0.0f;  // cols 205..207 pad
        }
    }
    __syncthreads();

    const int fg = t & 31;   // features 4*fg .. 4*fg+3
    const int mg = t >> 5;   // nodes 4*mg .. 4*mg+3
    float4 acc[4];
    const float4 bias = ((const float4*)b_in)[fg];
    acc[0] = acc[1] = acc[2] = acc[3] = bias;

    for (int kg = 0; kg < 51; ++kg) {  // k = 0..203
        float4 w[4];
        #pragma unroll
        for (int i = 0; i < 4; ++i)
            w[i] = ((const float4*)W_in)[(size_t)(4 * kg + i) * 32 + fg];
        #pragma unroll
        for (int mi = 0; mi < 4; ++mi) {
            const int m = mg * 4 + mi;
            const float4 a = *((const float4*)&x_s[m][4 * kg]);
            acc[mi] = fma4(w[0], a.x, acc[mi]);
            acc[mi] = fma4(w[1], a.y, acc[mi]);
            acc[mi] = fma4(w[2], a.z, acc[mi]);
            acc[mi] = fma4(w[3], a.w, acc[mi]);
        }
    }
    {   // k = 204
        const float4 w = ((const float4*)W_in)[204 * 32 + fg];
        #pragma unroll
        for (int mi = 0; mi < 4; ++mi) {
            const int m = mg * 4 + mi;
            acc[mi] = fma4(w, x_s[m][204], acc[mi]);
        }
    }

    const float4 gg = ((const float4*)g0)[fg];
    const float4 bb = ((const float4*)b0)[fg];
    #pragma unroll
    for (int mi = 0; mi < 4; ++mi) {
        const int m = mg * 4 + mi;
        const int node = node0 + m;
        const float4 u = acc[mi];
        float s = u.x + u.y + u.z + u.w;
        float q = u.x * u.x + u.y * u.y + u.z * u.z + u.w * u.w;
        #pragma unroll
        for (int off = 16; off >= 1; off >>= 1) {
            s += __shfl_xor(s, off);
            q += __shfl_xor(q, off);
        }
        const float mean = s * (1.0f / HID);
        const float var = q * (1.0f / HID) - mean * mean;
        const float rstd = rsqrtf(var + LN_EPS);
        float4 y;
        y.x = gelu_exact((u.x - mean) * rstd * gg.x + bb.x);
        y.y = gelu_exact((u.y - mean) * rstd * gg.y + bb.y);
        y.z = gelu_exact((u.z - mean) * rstd * gg.z + bb.z);
        y.w = gelu_exact((u.w - mean) * rstd * gg.w + bb.w);
        ((float4*)h_out)[(size_t)node * 32 + fg] = y;
    }
}

// ---------------- degree ----------------
__global__ __launch_bounds__(256) void degree_kernel(const int* __restrict__ tgt,
                                                     float* __restrict__ deg) {
    const int e = blockIdx.x * 256 + threadIdx.x;
    if (e < NE) atomicAdd(&deg[tgt[e]], 1.0f);
}

__global__ __launch_bounds__(256) void invdeg_kernel(float* __restrict__ deg) {
    const int i = blockIdx.x * 256 + threadIdx.x;
    if (i < NN) deg[i] = 1.0f / fmaxf(deg[i], 1.0f);
}

// ---------------- edge scatter: agg[tgt] += h[src] ----------------
__global__ __launch_bounds__(256) void scatter_kernel(const float* __restrict__ h,
                                                      const int* __restrict__ src,
                                                      const int* __restrict__ tgt,
                                                      float* __restrict__ agg) {
    const int tid = blockIdx.x * 256 + threadIdx.x;   // NE*32 threads
    const int e = tid >> 5;
    const int fg = tid & 31;
    if (e >= NE) return;
    const int s = src[e];
    const int d = tgt[e];
    const float4 v = ((const float4*)h)[(size_t)s * 32 + fg];
    float* out = agg + (size_t)d * HID + 4 * fg;
    atomicAdd(out + 0, v.x);
    atomicAdd(out + 1, v.y);
    atomicAdd(out + 2, v.z);
    atomicAdd(out + 3, v.w);
}

// ---------------- fused layer: h = LN(h + gelu(agg*invdeg @ Wl + bl + h @ Wr)) ----------------
__global__ __launch_bounds__(128) void layer_kernel(
    float* __restrict__ h, const float* __restrict__ agg,
    const float* __restrict__ inv_deg,
    const float* __restrict__ Wl, const float* __restrict__ bl,
    const float* __restrict__ Wr,
    const float* __restrict__ g, const float* __restrict__ b)
{
    __shared__ float4 agg_s[16][32];
    __shared__ float4 h_s[16][32];
    const int t = threadIdx.x;
    const int node0 = blockIdx.x * 16;

    for (int idx = t; idx < 16 * 32; idx += 128) {
        const int m = idx >> 5, c = idx & 31;
        const int node = node0 + m;
        float4 av = ((const float4*)agg)[(size_t)node * 32 + c];
        const float id = inv_deg[node];
        av.x *= id; av.y *= id; av.z *= id; av.w *= id;
        agg_s[m][c] = av;
        h_s[m][c] = ((const float4*)h)[(size_t)node * 32 + c];
    }
    __syncthreads();

    const int fg = t & 31;
    const int mg = t >> 5;
    float4 acc[4];
    const float4 bias = ((const float4*)bl)[fg];
    acc[0] = acc[1] = acc[2] = acc[3] = bias;

    for (int kg = 0; kg < 32; ++kg) {
        float4 wl[4], wr[4];
        #pragma unroll
        for (int i = 0; i < 4; ++i) {
            wl[i] = ((const float4*)Wl)[(size_t)(4 * kg + i) * 32 + fg];
            wr[i] = ((const float4*)Wr)[(size_t)(4 * kg + i) * 32 + fg];
        }
        #pragma unroll
        for (int mi = 0; mi < 4; ++mi) {
            const int m = mg * 4 + mi;
            const float4 a = agg_s[m][kg];
            const float4 x = h_s[m][kg];
            acc[mi] = fma4(wl[0], a.x, acc[mi]);
            acc[mi] = fma4(wl[1], a.y, acc[mi]);
            acc[mi] = fma4(wl[2], a.z, acc[mi]);
            acc[mi] = fma4(wl[3], a.w, acc[mi]);
            acc[mi] = fma4(wr[0], x.x, acc[mi]);
            acc[mi] = fma4(wr[1], x.y, acc[mi]);
            acc[mi] = fma4(wr[2], x.z, acc[mi]);
            acc[mi] = fma4(wr[3], x.w, acc[mi]);
        }
    }

    const float4 gg = ((const float4*)g)[fg];
    const float4 bb = ((const float4*)b)[fg];
    #pragma unroll
    for (int mi = 0; mi < 4; ++mi) {
        const int m = mg * 4 + mi;
        const int node = node0 + m;
        const float4 o = acc[mi];
        const float4 hv = h_s[m][fg];
        float4 tv;
        tv.x = hv.x + gelu_exact(o.x);
        tv.y = hv.y + gelu_exact(o.y);
        tv.z = hv.z + gelu_exact(o.z);
        tv.w = hv.w + gelu_exact(o.w);
        float s = tv.x + tv.y + tv.z + tv.w;
        float q = tv.x * tv.x + tv.y * tv.y + tv.z * tv.z + tv.w * tv.w;
        #pragma unroll
        for (int off = 16; off >= 1; off >>= 1) {
            s += __shfl_xor(s, off);
            q += __shfl_xor(q, off);
        }
        const float mean = s * (1.0f / HID);
        const float var = q * (1.0f / HID) - mean * mean;
        const float rstd = rsqrtf(var + LN_EPS);
        float4 y;
        y.x = (tv.x - mean) * rstd * gg.x + bb.x;
        y.y = (tv.y - mean) * rstd * gg.y + bb.y;
        y.z = (tv.z - mean) * rstd * gg.z + bb.z;
        y.w = (tv.w - mean) * rstd * gg.w + bb.w;
        ((float4*)h)[(size_t)node * 32 + fg] = y;
    }
}

extern "C" void kernel_launch(void* const* d_in, const int* in_sizes, int n_in,
                              void* d_out, int out_size, void* d_ws, size_t ws_size,
                              hipStream_t stream) {
    const float* node_feat = (const float*)d_in[0];
    const float* topo      = (const float*)d_in[1];
    const float* embed     = (const float*)d_in[2];
    const float* W_in      = (const float*)d_in[3];
    const float* b_in      = (const float*)d_in[4];
    const float* ln0_g     = (const float*)d_in[5];
    const float* ln0_b     = (const float*)d_in[6];
    const float* Wl        = (const float*)d_in[7];
    const float* bl        = (const float*)d_in[8];
    const float* Wr        = (const float*)d_in[9];
    const float* ln_g      = (const float*)d_in[10];
    const float* ln_b      = (const float*)d_in[11];
    const int*   opcode    = (const int*)d_in[12];
    const int*   edge      = (const int*)d_in[13];
    const int*   e_src = edge;
    const int*   e_tgt = edge + NE;

    float* h       = (float*)d_out;                         // 100000 x 128
    float* agg     = (float*)d_ws;                          // 51.2 MB
    float* inv_deg = (float*)((char*)d_ws + (size_t)NN * HID * sizeof(float));

    // input projection
    input_proj_kernel<<<NN / 16, 128, 0, stream>>>(
        node_feat, topo, embed, opcode, W_in, b_in, ln0_g, ln0_b, h);

    // degree -> inv_deg
    hipMemsetAsync(inv_deg, 0, (size_t)NN * sizeof(float), stream);
    degree_kernel<<<(NE + 255) / 256, 256, 0, stream>>>(e_tgt, inv_deg);
    invdeg_kernel<<<(NN + 255) / 256, 256, 0, stream>>>(inv_deg);

    for (int layer = 0; layer < 4; ++layer) {
        hipMemsetAsync(agg, 0, (size_t)NN * HID * sizeof(float), stream);
        scatter_kernel<<<(NE * 32) / 256, 256, 0, stream>>>(h, e_src, e_tgt, agg);
        layer_kernel<<<NN / 16, 128, 0, stream>>>(
            h, agg, inv_deg,
            Wl + (size_t)layer * HID * HID, bl + (size_t)layer * HID,
            Wr + (size_t)layer * HID * HID,
            ln_g + (size_t)layer * HID, ln_b + (size_t)layer * HID);
    }
}

// Round 2
// 1710.085 us; speedup vs baseline: 6.7190x; 6.7190x over previous
//
#include <hip/hip_runtime.h>
#include <cstdint>
#include <cstddef>

#define NN 100000
#define NE 1600000
#define FEAT 140
#define EMB 64
#define HID 128
#define LN_EPS 1e-5f

__device__ __forceinline__ float gelu_exact(float x) {
    return 0.5f * x * (1.0f + erff(x * 0.70710678118654752440f));
}

__device__ __forceinline__ float4 fma4(float4 w, float s, float4 acc) {
    acc.x = fmaf(s, w.x, acc.x);
    acc.y = fmaf(s, w.y, acc.y);
    acc.z = fmaf(s, w.z, acc.z);
    acc.w = fmaf(s, w.w, acc.w);
    return acc;
}

// ---------------- input projection: h = gelu(LN(concat @ W_in + b_in)) ----------------
__global__ __launch_bounds__(128) void input_proj_kernel(
    const float* __restrict__ node_feat, const float* __restrict__ topo,
    const float* __restrict__ embed, const int* __restrict__ opcode,
    const float* __restrict__ W_in, const float* __restrict__ b_in,
    const float* __restrict__ g0, const float* __restrict__ b0,
    float* __restrict__ h_out)
{
    __shared__ float x_s[16][208];   // 205 used, padded to 208 (zeros)
    const int t = threadIdx.x;
    const int node0 = blockIdx.x * 16;

    for (int m = 0; m < 16; ++m) {
        const int node = node0 + m;
        for (int c = t; c < FEAT; c += 128)
            x_s[m][c] = node_feat[(size_t)node * FEAT + c];
        if (t < EMB) {
            int op = opcode[node];
            op = min(max(op, 0), 127);
            x_s[m][FEAT + t] = embed[op * EMB + t];
        } else if (t == 64) {
            x_s[m][204] = topo[node];
        } else if (t >= 65 && t < 68) {
            x_s[m][140 + t] = 0.0f;  // cols 205..207 pad
        }
    }
    __syncthreads();

    const int fg = t & 31;   // features 4*fg .. 4*fg+3
    const int mg = t >> 5;   // nodes 4*mg .. 4*mg+3
    float4 acc[4];
    const float4 bias = ((const float4*)b_in)[fg];
    acc[0] = acc[1] = acc[2] = acc[3] = bias;

    for (int kg = 0; kg < 51; ++kg) {  // k = 0..203
        float4 w[4];
        #pragma unroll
        for (int i = 0; i < 4; ++i)
            w[i] = ((const float4*)W_in)[(size_t)(4 * kg + i) * 32 + fg];
        #pragma unroll
        for (int mi = 0; mi < 4; ++mi) {
            const int m = mg * 4 + mi;
            const float4 a = *((const float4*)&x_s[m][4 * kg]);
            acc[mi] = fma4(w[0], a.x, acc[mi]);
            acc[mi] = fma4(w[1], a.y, acc[mi]);
            acc[mi] = fma4(w[2], a.z, acc[mi]);
            acc[mi] = fma4(w[3], a.w, acc[mi]);
        }
    }
    {   // k = 204
        const float4 w = ((const float4*)W_in)[204 * 32 + fg];
        #pragma unroll
        for (int mi = 0; mi < 4; ++mi) {
            const int m = mg * 4 + mi;
            acc[mi] = fma4(w, x_s[m][204], acc[mi]);
        }
    }

    const float4 gg = ((const float4*)g0)[fg];
    const float4 bb = ((const float4*)b0)[fg];
    #pragma unroll
    for (int mi = 0; mi < 4; ++mi) {
        const int m = mg * 4 + mi;
        const int node = node0 + m;
        const float4 u = acc[mi];
        float s = u.x + u.y + u.z + u.w;
        float q = u.x * u.x + u.y * u.y + u.z * u.z + u.w * u.w;
        #pragma unroll
        for (int off = 16; off >= 1; off >>= 1) {
            s += __shfl_xor(s, off);
            q += __shfl_xor(q, off);
        }
        const float mean = s * (1.0f / HID);
        const float var = q * (1.0f / HID) - mean * mean;
        const float rstd = rsqrtf(var + LN_EPS);
        float4 y;
        y.x = gelu_exact((u.x - mean) * rstd * gg.x + bb.x);
        y.y = gelu_exact((u.y - mean) * rstd * gg.y + bb.y);
        y.z = gelu_exact((u.z - mean) * rstd * gg.z + bb.z);
        y.w = gelu_exact((u.w - mean) * rstd * gg.w + bb.w);
        ((float4*)h_out)[(size_t)node * 32 + fg] = y;
    }
}

// ---------------- CSR build ----------------
__global__ __launch_bounds__(256) void degree_int_kernel(const int* __restrict__ tgt,
                                                         int* __restrict__ deg) {
    const int e = blockIdx.x * 256 + threadIdx.x;
    if (e < NE) atomicAdd(&deg[tgt[e]], 1);
}

// single-block exclusive scan of deg -> offs & cursor; also inv_deg
__global__ __launch_bounds__(1024) void scan_kernel(const int* __restrict__ deg,
                                                    int* __restrict__ offs,
                                                    int* __restrict__ cursor,
                                                    float* __restrict__ inv_deg) {
    __shared__ int sums[1024];
    const int t = threadIdx.x;
    const int C = (NN + 1023) / 1024;   // 98
    const int beg = t * C;
    const int end = min(beg + C, NN);
    int s = 0;
    for (int i = beg; i < end; ++i) s += deg[i];
    sums[t] = s;
    __syncthreads();
    for (int off = 1; off < 1024; off <<= 1) {
        int u = (t >= off) ? sums[t - off] : 0;
        __syncthreads();
        sums[t] += u;
        __syncthreads();
    }
    int run = sums[t] - s;   // exclusive prefix of this chunk
    for (int i = beg; i < end; ++i) {
        offs[i] = run;
        cursor[i] = run;
        const int d = deg[i];
        inv_deg[i] = 1.0f / fmaxf((float)d, 1.0f);
        run += d;
    }
    if (end == NN && beg < NN) offs[NN] = run;
}

__global__ __launch_bounds__(256) void fill_csr_kernel(const int* __restrict__ src,
                                                       const int* __restrict__ tgt,
                                                       int* __restrict__ cursor,
                                                       int* __restrict__ csr) {
    const int e = blockIdx.x * 256 + threadIdx.x;
    if (e < NE) {
        const int pos = atomicAdd(&cursor[tgt[e]], 1);
        csr[pos] = src[e];
    }
}

// ---------------- gather: agg[n] = inv_deg[n] * sum_{s in csr[n]} h[s] ----------------
// one 64-lane wave per node; each lane owns a float2 column
__global__ __launch_bounds__(256) void gather_kernel(const float* __restrict__ h,
                                                     const int* __restrict__ csr,
                                                     const int* __restrict__ offs,
                                                     const float* __restrict__ inv_deg,
                                                     float* __restrict__ agg) {
    const int node = blockIdx.x * 4 + (threadIdx.x >> 6);
    const int lane = threadIdx.x & 63;
    if (node >= NN) return;
    const int beg = offs[node];
    const int end = offs[node + 1];
    const float2* hp = (const float2*)h;
    float2 acc = make_float2(0.0f, 0.0f);
    for (int j = beg; j < end; ++j) {
        const int s = csr[j];
        const float2 v = hp[(size_t)s * 64 + lane];
        acc.x += v.x;
        acc.y += v.y;
    }
    const float id = inv_deg[node];
    acc.x *= id;
    acc.y *= id;
    ((float2*)agg)[(size_t)node * 64 + lane] = acc;
}

// ---------------- fused layer: h = LN(h + gelu(agg @ Wl + bl + h @ Wr)) ----------------
__global__ __launch_bounds__(128) void layer_kernel(
    float* __restrict__ h, const float* __restrict__ agg,
    const float* __restrict__ Wl, const float* __restrict__ bl,
    const float* __restrict__ Wr,
    const float* __restrict__ g, const float* __restrict__ b)
{
    __shared__ float4 agg_s[16][32];
    __shared__ float4 h_s[16][32];
    const int t = threadIdx.x;
    const int node0 = blockIdx.x * 16;

    for (int idx = t; idx < 16 * 32; idx += 128) {
        const int m = idx >> 5, c = idx & 31;
        const int node = node0 + m;
        agg_s[m][c] = ((const float4*)agg)[(size_t)node * 32 + c];
        h_s[m][c] = ((const float4*)h)[(size_t)node * 32 + c];
    }
    __syncthreads();

    const int fg = t & 31;
    const int mg = t >> 5;
    float4 acc[4];
    const float4 bias = ((const float4*)bl)[fg];
    acc[0] = acc[1] = acc[2] = acc[3] = bias;

    for (int kg = 0; kg < 32; ++kg) {
        float4 wl[4], wr[4];
        #pragma unroll
        for (int i = 0; i < 4; ++i) {
            wl[i] = ((const float4*)Wl)[(size_t)(4 * kg + i) * 32 + fg];
            wr[i] = ((const float4*)Wr)[(size_t)(4 * kg + i) * 32 + fg];
        }
        #pragma unroll
        for (int mi = 0; mi < 4; ++mi) {
            const int m = mg * 4 + mi;
            const float4 a = agg_s[m][kg];
            const float4 x = h_s[m][kg];
            acc[mi] = fma4(wl[0], a.x, acc[mi]);
            acc[mi] = fma4(wl[1], a.y, acc[mi]);
            acc[mi] = fma4(wl[2], a.z, acc[mi]);
            acc[mi] = fma4(wl[3], a.w, acc[mi]);
            acc[mi] = fma4(wr[0], x.x, acc[mi]);
            acc[mi] = fma4(wr[1], x.y, acc[mi]);
            acc[mi] = fma4(wr[2], x.z, acc[mi]);
            acc[mi] = fma4(wr[3], x.w, acc[mi]);
        }
    }

    const float4 gg = ((const float4*)g)[fg];
    const float4 bb = ((const float4*)b)[fg];
    #pragma unroll
    for (int mi = 0; mi < 4; ++mi) {
        const int m = mg * 4 + mi;
        const int node = node0 + m;
        const float4 o = acc[mi];
        const float4 hv = h_s[m][fg];
        float4 tv;
        tv.x = hv.x + gelu_exact(o.x);
        tv.y = hv.y + gelu_exact(o.y);
        tv.z = hv.z + gelu_exact(o.z);
        tv.w = hv.w + gelu_exact(o.w);
        float s = tv.x + tv.y + tv.z + tv.w;
        float q = tv.x * tv.x + tv.y * tv.y + tv.z * tv.z + tv.w * tv.w;
        #pragma unroll
        for (int off = 16; off >= 1; off >>= 1) {
            s += __shfl_xor(s, off);
            q += __shfl_xor(q, off);
        }
        const float mean = s * (1.0f / HID);
        const float var = q * (1.0f / HID) - mean * mean;
        const float rstd = rsqrtf(var + LN_EPS);
        float4 y;
        y.x = (tv.x - mean) * rstd * gg.x + bb.x;
        y.y = (tv.y - mean) * rstd * gg.y + bb.y;
        y.z = (tv.z - mean) * rstd * gg.z + bb.z;
        y.w = (tv.w - mean) * rstd * gg.w + bb.w;
        ((float4*)h)[(size_t)node * 32 + fg] = y;
    }
}

extern "C" void kernel_launch(void* const* d_in, const int* in_sizes, int n_in,
                              void* d_out, int out_size, void* d_ws, size_t ws_size,
                              hipStream_t stream) {
    const float* node_feat = (const float*)d_in[0];
    const float* topo      = (const float*)d_in[1];
    const float* embed     = (const float*)d_in[2];
    const float* W_in      = (const float*)d_in[3];
    const float* b_in      = (const float*)d_in[4];
    const float* ln0_g     = (const float*)d_in[5];
    const float* ln0_b     = (const float*)d_in[6];
    const float* Wl        = (const float*)d_in[7];
    const float* bl        = (const float*)d_in[8];
    const float* Wr        = (const float*)d_in[9];
    const float* ln_g      = (const float*)d_in[10];
    const float* ln_b      = (const float*)d_in[11];
    const int*   opcode    = (const int*)d_in[12];
    const int*   edge      = (const int*)d_in[13];
    const int*   e_src = edge;
    const int*   e_tgt = edge + NE;

    float* h = (float*)d_out;                         // 100000 x 128

    // workspace layout (16B-aligned chunks)
    char* w = (char*)d_ws;
    float* agg     = (float*)w;                      w += (size_t)NN * HID * sizeof(float);  // 51.2 MB
    float* inv_deg = (float*)w;                      w += 400016;
    int*   deg_i   = (int*)w;                        w += 400016;
    int*   offs    = (int*)w;                        w += 400016;   // NN+1 ints
    int*   cursor  = (int*)w;                        w += 400016;
    int*   csr     = (int*)w;                        w += (size_t)NE * sizeof(int);          // 6.4 MB

    // input projection (independent of CSR build)
    input_proj_kernel<<<NN / 16, 128, 0, stream>>>(
        node_feat, topo, embed, opcode, W_in, b_in, ln0_g, ln0_b, h);

    // CSR build
    hipMemsetAsync(deg_i, 0, (size_t)NN * sizeof(int), stream);
    degree_int_kernel<<<(NE + 255) / 256, 256, 0, stream>>>(e_tgt, deg_i);
    scan_kernel<<<1, 1024, 0, stream>>>(deg_i, offs, cursor, inv_deg);
    fill_csr_kernel<<<(NE + 255) / 256, 256, 0, stream>>>(e_src, e_tgt, cursor, csr);

    for (int layer = 0; layer < 4; ++layer) {
        gather_kernel<<<NN / 4, 256, 0, stream>>>(h, csr, offs, inv_deg, agg);
        layer_kernel<<<NN / 16, 128, 0, stream>>>(
            h, agg,
            Wl + (size_t)layer * HID * HID, bl + (size_t)layer * HID,
            Wr + (size_t)layer * HID * HID,
            ln_g + (size_t)layer * HID, ln_b + (size_t)layer * HID);
    }
}

// Round 3
// 1386.380 us; speedup vs baseline: 8.2878x; 1.2335x over previous
//
#include <hip/hip_runtime.h>
#include <cstdint>
#include <cstddef>

#define NN 100000
#define NE 1600000
#define FEAT 140
#define EMB 64
#define HID 128
#define LN_EPS 1e-5f
#define SCAN_NBLK 98   // ceil(NN/1024)

typedef unsigned int uint;
typedef unsigned short ushort;

__device__ __forceinline__ float gelu_exact(float x) {
    return 0.5f * x * (1.0f + erff(x * 0.70710678118654752440f));
}

__device__ __forceinline__ float4 fma4(float4 w, float s, float4 acc) {
    acc.x = fmaf(s, w.x, acc.x);
    acc.y = fmaf(s, w.y, acc.y);
    acc.z = fmaf(s, w.z, acc.z);
    acc.w = fmaf(s, w.w, acc.w);
    return acc;
}

__device__ __forceinline__ ushort f2bf(float f) {
    // round-to-nearest-even bf16
    uint u = __float_as_uint(f);
    uint r = (u + 0x7fff + ((u >> 16) & 1)) >> 16;
    return (ushort)r;
}

__device__ __forceinline__ float bf2f(ushort u) {
    return __uint_as_float(((uint)u) << 16);
}

// ---------------- input projection: h = gelu(LN(concat @ W_in + b_in)) ----------------
__global__ __launch_bounds__(128) void input_proj_kernel(
    const float* __restrict__ node_feat, const float* __restrict__ topo,
    const float* __restrict__ embed, const int* __restrict__ opcode,
    const float* __restrict__ W_in, const float* __restrict__ b_in,
    const float* __restrict__ g0, const float* __restrict__ b0,
    float* __restrict__ h_out, ushort* __restrict__ hb_out)
{
    __shared__ float x_s[16][208];   // 205 used, padded to 208 (zeros)
    const int t = threadIdx.x;
    const int node0 = blockIdx.x * 16;

    for (int m = 0; m < 16; ++m) {
        const int node = node0 + m;
        for (int c = t; c < FEAT; c += 128)
            x_s[m][c] = node_feat[(size_t)node * FEAT + c];
        if (t < EMB) {
            int op = opcode[node];
            op = min(max(op, 0), 127);
            x_s[m][FEAT + t] = embed[op * EMB + t];
        } else if (t == 64) {
            x_s[m][204] = topo[node];
        } else if (t >= 65 && t < 68) {
            x_s[m][140 + t] = 0.0f;  // cols 205..207 pad
        }
    }
    __syncthreads();

    const int fg = t & 31;   // features 4*fg .. 4*fg+3
    const int mg = t >> 5;   // nodes 4*mg .. 4*mg+3
    float4 acc[4];
    const float4 bias = ((const float4*)b_in)[fg];
    acc[0] = acc[1] = acc[2] = acc[3] = bias;

    for (int kg = 0; kg < 51; ++kg) {  // k = 0..203
        float4 w[4];
        #pragma unroll
        for (int i = 0; i < 4; ++i)
            w[i] = ((const float4*)W_in)[(size_t)(4 * kg + i) * 32 + fg];
        #pragma unroll
        for (int mi = 0; mi < 4; ++mi) {
            const int m = mg * 4 + mi;
            const float4 a = *((const float4*)&x_s[m][4 * kg]);
            acc[mi] = fma4(w[0], a.x, acc[mi]);
            acc[mi] = fma4(w[1], a.y, acc[mi]);
            acc[mi] = fma4(w[2], a.z, acc[mi]);
            acc[mi] = fma4(w[3], a.w, acc[mi]);
        }
    }
    {   // k = 204
        const float4 w = ((const float4*)W_in)[204 * 32 + fg];
        #pragma unroll
        for (int mi = 0; mi < 4; ++mi) {
            const int m = mg * 4 + mi;
            acc[mi] = fma4(w, x_s[m][204], acc[mi]);
        }
    }

    const float4 gg = ((const float4*)g0)[fg];
    const float4 bb = ((const float4*)b0)[fg];
    #pragma unroll
    for (int mi = 0; mi < 4; ++mi) {
        const int m = mg * 4 + mi;
        const int node = node0 + m;
        const float4 u = acc[mi];
        float s = u.x + u.y + u.z + u.w;
        float q = u.x * u.x + u.y * u.y + u.z * u.z + u.w * u.w;
        #pragma unroll
        for (int off = 16; off >= 1; off >>= 1) {
            s += __shfl_xor(s, off);
            q += __shfl_xor(q, off);
        }
        const float mean = s * (1.0f / HID);
        const float var = q * (1.0f / HID) - mean * mean;
        const float rstd = rsqrtf(var + LN_EPS);
        float4 y;
        y.x = gelu_exact((u.x - mean) * rstd * gg.x + bb.x);
        y.y = gelu_exact((u.y - mean) * rstd * gg.y + bb.y);
        y.z = gelu_exact((u.z - mean) * rstd * gg.z + bb.z);
        y.w = gelu_exact((u.w - mean) * rstd * gg.w + bb.w);
        ((float4*)h_out)[(size_t)node * 32 + fg] = y;
        ushort4 us;
        us.x = f2bf(y.x); us.y = f2bf(y.y); us.z = f2bf(y.z); us.w = f2bf(y.w);
        ((ushort4*)hb_out)[(size_t)node * 32 + fg] = us;
    }
}

// ---------------- CSR build ----------------
__global__ __launch_bounds__(256) void degree_int_kernel(const int* __restrict__ tgt,
                                                         int* __restrict__ deg) {
    const int e = blockIdx.x * 256 + threadIdx.x;
    if (e < NE) atomicAdd(&deg[tgt[e]], 1);
}

// k1: per-block reduce of 1024 degrees
__global__ __launch_bounds__(1024) void deg_reduce_kernel(const int* __restrict__ deg,
                                                          int* __restrict__ bsum) {
    const int i = blockIdx.x * 1024 + threadIdx.x;
    int v = (i < NN) ? deg[i] : 0;
    #pragma unroll
    for (int off = 32; off >= 1; off >>= 1) v += __shfl_down(v, off);
    __shared__ int wsum[16];
    const int lane = threadIdx.x & 63, wid = threadIdx.x >> 6;
    if (lane == 0) wsum[wid] = v;
    __syncthreads();
    if (threadIdx.x < 16) {
        int s = wsum[threadIdx.x];
        #pragma unroll
        for (int off = 8; off >= 1; off >>= 1) s += __shfl_down(s, off, 16);
        if (threadIdx.x == 0) bsum[blockIdx.x] = s;
    }
}

// k2: scan 98 block sums (one block)
__global__ __launch_bounds__(128) void bsum_scan_kernel(const int* __restrict__ bsum,
                                                        int* __restrict__ boff,
                                                        int* __restrict__ offs) {
    __shared__ int s_[128];
    const int t = threadIdx.x;
    int v = (t < SCAN_NBLK) ? bsum[t] : 0;
    s_[t] = v;
    __syncthreads();
    for (int off = 1; off < 128; off <<= 1) {
        int u = (t >= off) ? s_[t - off] : 0;
        __syncthreads();
        s_[t] += u;
        __syncthreads();
    }
    if (t < SCAN_NBLK) boff[t] = s_[t] - v;   // exclusive
    if (t == 0) offs[NN] = NE;
}

// k3: per-block exclusive scan + apply
__global__ __launch_bounds__(1024) void scan_apply_kernel(const int* __restrict__ deg,
                                                          const int* __restrict__ boff,
                                                          int* __restrict__ offs,
                                                          int* __restrict__ cursor,
                                                          float* __restrict__ inv_deg) {
    const int i = blockIdx.x * 1024 + threadIdx.x;
    const int lane = threadIdx.x & 63, wid = threadIdx.x >> 6;
    int v = (i < NN) ? deg[i] : 0;
    int x = v;
    #pragma unroll
    for (int off = 1; off < 64; off <<= 1) {
        int y = __shfl_up(x, off);
        if (lane >= off) x += y;
    }
    __shared__ int wsum[16];
    __shared__ int woff[16];
    if (lane == 63) wsum[wid] = x;
    __syncthreads();
    if (threadIdx.x < 16) {
        const int own = wsum[threadIdx.x];
        int s = own;
        #pragma unroll
        for (int off = 1; off < 16; off <<= 1) {
            int y = __shfl_up(s, off, 16);
            if (threadIdx.x >= off) s += y;
        }
        woff[threadIdx.x] = s - own;
    }
    __syncthreads();
    if (i < NN) {
        const int ex = (x - v) + woff[wid] + boff[blockIdx.x];
        offs[i] = ex;
        cursor[i] = ex;
        inv_deg[i] = 1.0f / fmaxf((float)v, 1.0f);
    }
}

__global__ __launch_bounds__(256) void fill_csr_kernel(const int* __restrict__ src,
                                                       const int* __restrict__ tgt,
                                                       int* __restrict__ cursor,
                                                       int* __restrict__ csr) {
    const int e = blockIdx.x * 256 + threadIdx.x;
    if (e < NE) {
        const int pos = atomicAdd(&cursor[tgt[e]], 1);
        csr[pos] = src[e];
    }
}

// ---------------- gather: aggb[n] = bf16( inv_deg[n] * sum_{s in csr[n]} hb[s] ) ----------------
// one 64-lane wave per node; each lane owns 2 bf16 columns (one packed uint)
__global__ __launch_bounds__(256) void gather_kernel(const ushort* __restrict__ hb,
                                                     const int* __restrict__ csr,
                                                     const int* __restrict__ offs,
                                                     const float* __restrict__ inv_deg,
                                                     ushort* __restrict__ aggb) {
    const int node = blockIdx.x * 4 + (threadIdx.x >> 6);
    const int lane = threadIdx.x & 63;
    if (node >= NN) return;
    const int beg = offs[node];
    const int end = offs[node + 1];
    const uint* hp = (const uint*)hb;
    float ax = 0.0f, ay = 0.0f;
    for (int j = beg; j < end; ++j) {
        const int s = csr[j];
        const uint u = hp[(size_t)s * 64 + lane];
        ax += bf2f((ushort)(u & 0xffffu));
        ay += bf2f((ushort)(u >> 16));
    }
    const float id = inv_deg[node];
    const uint lo = f2bf(ax * id);
    const uint hi = f2bf(ay * id);
    ((uint*)aggb)[(size_t)node * 64 + lane] = lo | (hi << 16);
}

// ---------------- fused layer: h = LN(h + gelu(agg @ Wl + bl + h @ Wr)) ----------------
__global__ __launch_bounds__(128) void layer_kernel(
    float* __restrict__ h, ushort* __restrict__ hb,
    const ushort* __restrict__ aggb,
    const float* __restrict__ Wl, const float* __restrict__ bl,
    const float* __restrict__ Wr,
    const float* __restrict__ g, const float* __restrict__ b)
{
    __shared__ float4 agg_s[16][32];
    __shared__ float4 h_s[16][32];
    const int t = threadIdx.x;
    const int node0 = blockIdx.x * 16;

    for (int idx = t; idx < 16 * 32; idx += 128) {
        const int m = idx >> 5, c = idx & 31;
        const int node = node0 + m;
        const uint2 av = ((const uint2*)aggb)[(size_t)node * 32 + c];
        float4 a;
        a.x = bf2f((ushort)(av.x & 0xffffu));
        a.y = bf2f((ushort)(av.x >> 16));
        a.z = bf2f((ushort)(av.y & 0xffffu));
        a.w = bf2f((ushort)(av.y >> 16));
        agg_s[m][c] = a;
        h_s[m][c] = ((const float4*)h)[(size_t)node * 32 + c];
    }
    __syncthreads();

    const int fg = t & 31;
    const int mg = t >> 5;
    float4 acc[4];
    const float4 bias = ((const float4*)bl)[fg];
    acc[0] = acc[1] = acc[2] = acc[3] = bias;

    for (int kg = 0; kg < 32; ++kg) {
        float4 wl[4], wr[4];
        #pragma unroll
        for (int i = 0; i < 4; ++i) {
            wl[i] = ((const float4*)Wl)[(size_t)(4 * kg + i) * 32 + fg];
            wr[i] = ((const float4*)Wr)[(size_t)(4 * kg + i) * 32 + fg];
        }
        #pragma unroll
        for (int mi = 0; mi < 4; ++mi) {
            const int m = mg * 4 + mi;
            const float4 a = agg_s[m][kg];
            const float4 x = h_s[m][kg];
            acc[mi] = fma4(wl[0], a.x, acc[mi]);
            acc[mi] = fma4(wl[1], a.y, acc[mi]);
            acc[mi] = fma4(wl[2], a.z, acc[mi]);
            acc[mi] = fma4(wl[3], a.w, acc[mi]);
            acc[mi] = fma4(wr[0], x.x, acc[mi]);
            acc[mi] = fma4(wr[1], x.y, acc[mi]);
            acc[mi] = fma4(wr[2], x.z, acc[mi]);
            acc[mi] = fma4(wr[3], x.w, acc[mi]);
        }
    }

    const float4 gg = ((const float4*)g)[fg];
    const float4 bb = ((const float4*)b)[fg];
    #pragma unroll
    for (int mi = 0; mi < 4; ++mi) {
        const int m = mg * 4 + mi;
        const int node = node0 + m;
        const float4 o = acc[mi];
        const float4 hv = h_s[m][fg];
        float4 tv;
        tv.x = hv.x + gelu_exact(o.x);
        tv.y = hv.y + gelu_exact(o.y);
        tv.z = hv.z + gelu_exact(o.z);
        tv.w = hv.w + gelu_exact(o.w);
        float s = tv.x + tv.y + tv.z + tv.w;
        float q = tv.x * tv.x + tv.y * tv.y + tv.z * tv.z + tv.w * tv.w;
        #pragma unroll
        for (int off = 16; off >= 1; off >>= 1) {
            s += __shfl_xor(s, off);
            q += __shfl_xor(q, off);
        }
        const float mean = s * (1.0f / HID);
        const float var = q * (1.0f / HID) - mean * mean;
        const float rstd = rsqrtf(var + LN_EPS);
        float4 y;
        y.x = (tv.x - mean) * rstd * gg.x + bb.x;
        y.y = (tv.y - mean) * rstd * gg.y + bb.y;
        y.z = (tv.z - mean) * rstd * gg.z + bb.z;
        y.w = (tv.w - mean) * rstd * gg.w + bb.w;
        ((float4*)h)[(size_t)node * 32 + fg] = y;
        ushort4 us;
        us.x = f2bf(y.x); us.y = f2bf(y.y); us.z = f2bf(y.z); us.w = f2bf(y.w);
        ((ushort4*)hb)[(size_t)node * 32 + fg] = us;
    }
}

extern "C" void kernel_launch(void* const* d_in, const int* in_sizes, int n_in,
                              void* d_out, int out_size, void* d_ws, size_t ws_size,
                              hipStream_t stream) {
    const float* node_feat = (const float*)d_in[0];
    const float* topo      = (const float*)d_in[1];
    const float* embed     = (const float*)d_in[2];
    const float* W_in      = (const float*)d_in[3];
    const float* b_in      = (const float*)d_in[4];
    const float* ln0_g     = (const float*)d_in[5];
    const float* ln0_b     = (const float*)d_in[6];
    const float* Wl        = (const float*)d_in[7];
    const float* bl        = (const float*)d_in[8];
    const float* Wr        = (const float*)d_in[9];
    const float* ln_g      = (const float*)d_in[10];
    const float* ln_b      = (const float*)d_in[11];
    const int*   opcode    = (const int*)d_in[12];
    const int*   edge      = (const int*)d_in[13];
    const int*   e_src = edge;
    const int*   e_tgt = edge + NE;

    float* h = (float*)d_out;                         // 100000 x 128 f32

    // workspace layout (16B-aligned chunks)
    char* w = (char*)d_ws;
    ushort* hb     = (ushort*)w;                     w += (size_t)NN * HID * sizeof(ushort);  // 25.6 MB
    ushort* aggb   = (ushort*)w;                     w += (size_t)NN * HID * sizeof(ushort);  // 25.6 MB
    float* inv_deg = (float*)w;                      w += 400016;
    int*   deg_i   = (int*)w;                        w += 400016;
    int*   offs    = (int*)w;                        w += 400016;   // NN+1 ints
    int*   cursor  = (int*)w;                        w += 400016;
    int*   bsum    = (int*)w;                        w += 1024;
    int*   boff    = (int*)w;                        w += 1024;
    int*   csr     = (int*)w;                        w += (size_t)NE * sizeof(int);           // 6.4 MB

    // input projection (independent of CSR build)
    input_proj_kernel<<<NN / 16, 128, 0, stream>>>(
        node_feat, topo, embed, opcode, W_in, b_in, ln0_g, ln0_b, h, hb);

    // CSR build
    hipMemsetAsync(deg_i, 0, (size_t)NN * sizeof(int), stream);
    degree_int_kernel<<<(NE + 255) / 256, 256, 0, stream>>>(e_tgt, deg_i);
    deg_reduce_kernel<<<SCAN_NBLK, 1024, 0, stream>>>(deg_i, bsum);
    bsum_scan_kernel<<<1, 128, 0, stream>>>(bsum, boff, offs);
    scan_apply_kernel<<<SCAN_NBLK, 1024, 0, stream>>>(deg_i, boff, offs, cursor, inv_deg);
    fill_csr_kernel<<<(NE + 255) / 256, 256, 0, stream>>>(e_src, e_tgt, cursor, csr);

    for (int layer = 0; layer < 4; ++layer) {
        gather_kernel<<<NN / 4, 256, 0, stream>>>(hb, csr, offs, inv_deg, aggb);
        layer_kernel<<<NN / 16, 128, 0, stream>>>(
            h, hb, aggb,
            Wl + (size_t)layer * HID * HID, bl + (size_t)layer * HID,
            Wr + (size_t)layer * HID * HID,
            ln_g + (size_t)layer * HID, ln_b + (size_t)layer * HID);
    }
}

// Round 4
// 1064.089 us; speedup vs baseline: 10.7981x; 1.3029x over previous
//
#include <hip/hip_runtime.h>
#include <cstdint>
#include <cstddef>

#define NN 100000
#define NE 1600000
#define FEAT 140
#define EMB 64
#define HID 128
#define LN_EPS 1e-5f
#define SCAN_NBLK 98   // ceil(NN/1024)

typedef unsigned int uint;
typedef unsigned short ushort;
using short8 = __attribute__((ext_vector_type(8))) short;
using f32x4  = __attribute__((ext_vector_type(4))) float;

__device__ __forceinline__ float gelu_exact(float x) {
    return 0.5f * x * (1.0f + erff(x * 0.70710678118654752440f));
}

__device__ __forceinline__ ushort f2bf(float f) {
    uint u = __float_as_uint(f);
    uint r = (u + 0x7fff + ((u >> 16) & 1)) >> 16;
    return (ushort)r;
}

__device__ __forceinline__ float bf2f(ushort u) {
    return __uint_as_float(((uint)u) << 16);
}

// ================= weight packing into MFMA B-fragment order =================
// frag layout per (kk, c): lane l holds 8 bf16, k = kk*32 + (l>>4)*8 + j, col = c*16 + (l&15)
// winp: [7][8][64][8]  (K=224 padded, cols k>=205 zero)
// wcat: [4 layers][8][8][64][8]  (K=256 = [Wl rows 0..127 ; Wr rows 0..127])
__global__ __launch_bounds__(256) void pack_weights_kernel(
    const float* __restrict__ W_in, const float* __restrict__ Wl,
    const float* __restrict__ Wr,
    ushort* __restrict__ winp, ushort* __restrict__ wcat)
{
    const int tid = blockIdx.x * 256 + threadIdx.x;
    const int NIN = 7 * 8 * 64;        // 3584
    const int NL  = 8 * 8 * 64;        // 4096
    if (tid < NIN) {
        const int kk = tid >> 9;
        const int c  = (tid >> 6) & 7;
        const int l  = tid & 63;
        const int kbase = kk * 32 + (l >> 4) * 8;
        const int col = c * 16 + (l & 15);
        short8 v;
        #pragma unroll
        for (int j = 0; j < 8; ++j) {
            const int k = kbase + j;
            v[j] = (k < 205) ? (short)f2bf(W_in[k * 128 + col]) : (short)0;
        }
        *(short8*)(winp + (size_t)tid * 8) = v;
    } else if (tid < NIN + 4 * NL) {
        const int t2 = tid - NIN;
        const int layer = t2 >> 12;
        const int r = t2 & (NL - 1);
        const int kk = r >> 9;
        const int c  = (r >> 6) & 7;
        const int l  = r & 63;
        const int kbase = kk * 32 + (l >> 4) * 8;
        const int col = c * 16 + (l & 15);
        short8 v;
        #pragma unroll
        for (int j = 0; j < 8; ++j) {
            const int k = kbase + j;
            const float x = (k < 128)
                ? Wl[(size_t)layer * 16384 + k * 128 + col]
                : Wr[(size_t)layer * 16384 + (k - 128) * 128 + col];
            v[j] = (short)f2bf(x);
        }
        *(short8*)(wcat + (size_t)t2 * 8) = v;
    }
}

// ================= input projection (MFMA): h = gelu(LN(concat @ W_in + b_in)) =================
// 64 nodes/block, 256 threads (4 waves), K padded to 224, LDS row stride 232 bf16
__global__ __launch_bounds__(256) void input_proj_mfma(
    const float* __restrict__ nf, const float* __restrict__ topo,
    const float* __restrict__ embed, const int* __restrict__ opcode,
    const ushort* __restrict__ Wp, const float* __restrict__ b_in,
    const float* __restrict__ g0, const float* __restrict__ b0,
    float* __restrict__ h_out, ushort* __restrict__ hb_out)
{
    __shared__ ushort xs[64 * 232];
    const int t = threadIdx.x;
    const int node0 = blockIdx.x * 64;

    // stage node_feat (140 f32 = 35 float4 per row) -> bf16
    for (int idx = t; idx < 64 * 35; idx += 256) {
        const int row = idx / 35, c = idx - row * 35;
        const int node = min(node0 + row, NN - 1);
        const float4 v = ((const float4*)nf)[(size_t)node * 35 + c];
        ushort* p = &xs[row * 232 + c * 4];
        p[0] = f2bf(v.x); p[1] = f2bf(v.y); p[2] = f2bf(v.z); p[3] = f2bf(v.w);
    }
    // stage embed (64 = 16 float4 per row)
    for (int idx = t; idx < 64 * 16; idx += 256) {
        const int row = idx >> 4, c = idx & 15;
        const int node = min(node0 + row, NN - 1);
        int op = opcode[node];
        op = min(max(op, 0), 127);
        const float4 v = ((const float4*)embed)[op * 16 + c];
        ushort* p = &xs[row * 232 + 140 + c * 4];
        p[0] = f2bf(v.x); p[1] = f2bf(v.y); p[2] = f2bf(v.z); p[3] = f2bf(v.w);
    }
    // topo at col 204; zeros for cols 205..223
    if (t < 64) {
        const int node = min(node0 + t, NN - 1);
        xs[t * 232 + 204] = f2bf(topo[node]);
    }
    for (int idx = t; idx < 64 * 19; idx += 256) {
        const int row = idx / 19, c = 205 + (idx - row * 19);
        xs[row * 232 + c] = 0;
    }
    __syncthreads();

    const int w = t >> 6, l = t & 63;
    const int gq = l >> 4, li = l & 15;

    f32x4 acc[8];
    #pragma unroll
    for (int c = 0; c < 8; ++c) acc[c] = (f32x4){0.f, 0.f, 0.f, 0.f};

    const short8* Bp = (const short8*)Wp;
    for (int kk = 0; kk < 7; ++kk) {
        const short8 a = *(const short8*)&xs[(w * 16 + li) * 232 + kk * 32 + gq * 8];
        #pragma unroll
        for (int c = 0; c < 8; ++c) {
            const short8 b = Bp[(kk * 8 + c) * 64 + l];
            acc[c] = __builtin_amdgcn_mfma_f32_16x16x32_bf16(a, b, acc[c], 0, 0, 0);
        }
    }

    // epilogue: u = acc + bias; LN over 128 cols; gelu; store
    float bias[8], gam[8], bet[8];
    #pragma unroll
    for (int c = 0; c < 8; ++c) {
        bias[c] = b_in[c * 16 + li];
        gam[c]  = g0[c * 16 + li];
        bet[c]  = b0[c * 16 + li];
    }
    float s[4] = {0, 0, 0, 0}, q[4] = {0, 0, 0, 0};
    #pragma unroll
    for (int c = 0; c < 8; ++c)
        #pragma unroll
        for (int r = 0; r < 4; ++r) {
            const float u = acc[c][r] + bias[c];
            acc[c][r] = u;
            s[r] += u;
            q[r] += u * u;
        }
    #pragma unroll
    for (int off = 1; off < 16; off <<= 1)
        #pragma unroll
        for (int r = 0; r < 4; ++r) {
            s[r] += __shfl_xor(s[r], off);
            q[r] += __shfl_xor(q[r], off);
        }
    #pragma unroll
    for (int r = 0; r < 4; ++r) {
        const int node = node0 + w * 16 + gq * 4 + r;
        if (node >= NN) continue;
        const float mean = s[r] * (1.0f / HID);
        const float var  = q[r] * (1.0f / HID) - mean * mean;
        const float rstd = rsqrtf(var + LN_EPS);
        #pragma unroll
        for (int c = 0; c < 8; ++c) {
            const float y = gelu_exact((acc[c][r] - mean) * rstd * gam[c] + bet[c]);
            h_out[(size_t)node * 128 + c * 16 + li] = y;
            hb_out[(size_t)node * 128 + c * 16 + li] = f2bf(y);
        }
    }
}

// ================= CSR build =================
__global__ __launch_bounds__(256) void degree_int_kernel(const int* __restrict__ tgt,
                                                         int* __restrict__ deg) {
    const int e = blockIdx.x * 256 + threadIdx.x;
    if (e < NE) atomicAdd(&deg[tgt[e]], 1);
}

__global__ __launch_bounds__(1024) void deg_reduce_kernel(const int* __restrict__ deg,
                                                          int* __restrict__ bsum) {
    const int i = blockIdx.x * 1024 + threadIdx.x;
    int v = (i < NN) ? deg[i] : 0;
    #pragma unroll
    for (int off = 32; off >= 1; off >>= 1) v += __shfl_down(v, off);
    __shared__ int wsum[16];
    const int lane = threadIdx.x & 63, wid = threadIdx.x >> 6;
    if (lane == 0) wsum[wid] = v;
    __syncthreads();
    if (threadIdx.x < 16) {
        int s = wsum[threadIdx.x];
        #pragma unroll
        for (int off = 8; off >= 1; off >>= 1) s += __shfl_down(s, off, 16);
        if (threadIdx.x == 0) bsum[blockIdx.x] = s;
    }
}

__global__ __launch_bounds__(128) void bsum_scan_kernel(const int* __restrict__ bsum,
                                                        int* __restrict__ boff,
                                                        int* __restrict__ offs) {
    __shared__ int s_[128];
    const int t = threadIdx.x;
    int v = (t < SCAN_NBLK) ? bsum[t] : 0;
    s_[t] = v;
    __syncthreads();
    for (int off = 1; off < 128; off <<= 1) {
        int u = (t >= off) ? s_[t - off] : 0;
        __syncthreads();
        s_[t] += u;
        __syncthreads();
    }
    if (t < SCAN_NBLK) boff[t] = s_[t] - v;
    if (t == 0) offs[NN] = NE;
}

__global__ __launch_bounds__(1024) void scan_apply_kernel(const int* __restrict__ deg,
                                                          const int* __restrict__ boff,
                                                          int* __restrict__ offs,
                                                          int* __restrict__ cursor,
                                                          float* __restrict__ inv_deg) {
    const int i = blockIdx.x * 1024 + threadIdx.x;
    const int lane = threadIdx.x & 63, wid = threadIdx.x >> 6;
    int v = (i < NN) ? deg[i] : 0;
    int x = v;
    #pragma unroll
    for (int off = 1; off < 64; off <<= 1) {
        int y = __shfl_up(x, off);
        if (lane >= off) x += y;
    }
    __shared__ int wsum[16];
    __shared__ int woff[16];
    if (lane == 63) wsum[wid] = x;
    __syncthreads();
    if (threadIdx.x < 16) {
        const int own = wsum[threadIdx.x];
        int s = own;
        #pragma unroll
        for (int off = 1; off < 16; off <<= 1) {
            int y = __shfl_up(s, off, 16);
            if (threadIdx.x >= off) s += y;
        }
        woff[threadIdx.x] = s - own;
    }
    __syncthreads();
    if (i < NN) {
        const int ex = (x - v) + woff[wid] + boff[blockIdx.x];
        offs[i] = ex;
        cursor[i] = ex;
        inv_deg[i] = 1.0f / fmaxf((float)v, 1.0f);
    }
}

__global__ __launch_bounds__(256) void fill_csr_kernel(const int* __restrict__ src,
                                                       const int* __restrict__ tgt,
                                                       int* __restrict__ cursor,
                                                       int* __restrict__ csr) {
    const int e = blockIdx.x * 256 + threadIdx.x;
    if (e < NE) {
        const int pos = atomicAdd(&cursor[tgt[e]], 1);
        csr[pos] = src[e];
    }
}

// ================= gather: aggb[n] = bf16( inv_deg[n] * sum hb[src] ) =================
__global__ __launch_bounds__(256) void gather_kernel(const ushort* __restrict__ hb,
                                                     const int* __restrict__ csr,
                                                     const int* __restrict__ offs,
                                                     const float* __restrict__ inv_deg,
                                                     ushort* __restrict__ aggb) {
    const int node = blockIdx.x * 4 + (threadIdx.x >> 6);
    const int lane = threadIdx.x & 63;
    if (node >= NN) return;
    const int beg = offs[node];
    const int end = offs[node + 1];
    const uint* hp = (const uint*)hb;
    float ax = 0.0f, ay = 0.0f;
    for (int j = beg; j < end; ++j) {
        const int s = csr[j];
        const uint u = hp[(size_t)s * 64 + lane];
        ax += bf2f((ushort)(u & 0xffffu));
        ay += bf2f((ushort)(u >> 16));
    }
    const float id = inv_deg[node];
    const uint lo = f2bf(ax * id);
    const uint hi = f2bf(ay * id);
    ((uint*)aggb)[(size_t)node * 64 + lane] = lo | (hi << 16);
}

// ================= fused layer (MFMA): h = LN(h + gelu([agg|h] @ [Wl;Wr] + bl)) =================
// 64 nodes/block, 256 threads (4 waves), K=256, A frags straight from global bf16
__global__ __launch_bounds__(256) void layer_mfma(
    float* __restrict__ h, ushort* __restrict__ hb,
    const ushort* __restrict__ aggb, const ushort* __restrict__ Wp,
    const float* __restrict__ bl,
    const float* __restrict__ g, const float* __restrict__ b)
{
    const int t = threadIdx.x;
    const int w = t >> 6, l = t & 63;
    const int gq = l >> 4, li = l & 15;
    const int node0 = blockIdx.x * 64;
    const int ar = min(node0 + w * 16 + li, NN - 1);   // A-frag row

    f32x4 acc[8];
    #pragma unroll
    for (int c = 0; c < 8; ++c) acc[c] = (f32x4){0.f, 0.f, 0.f, 0.f};

    const short8* Bp = (const short8*)Wp;
    const short8* Ag = (const short8*)aggb;   // 16 short8-chunks per node row
    const short8* Hg = (const short8*)hb;
    #pragma unroll
    for (int kk = 0; kk < 8; ++kk) {
        const short8 a = (kk < 4) ? Ag[(size_t)ar * 16 + kk * 4 + gq]
                                  : Hg[(size_t)ar * 16 + (kk - 4) * 4 + gq];
        #pragma unroll
        for (int c = 0; c < 8; ++c) {
            const short8 bf = Bp[(kk * 8 + c) * 64 + l];
            acc[c] = __builtin_amdgcn_mfma_f32_16x16x32_bf16(a, bf, acc[c], 0, 0, 0);
        }
    }

    float bias[8], gam[8], bet[8];
    #pragma unroll
    for (int c = 0; c < 8; ++c) {
        bias[c] = bl[c * 16 + li];
        gam[c]  = g[c * 16 + li];
        bet[c]  = b[c * 16 + li];
    }
    float s[4] = {0, 0, 0, 0}, q[4] = {0, 0, 0, 0};
    #pragma unroll
    for (int r = 0; r < 4; ++r) {
        const int nd = min(node0 + w * 16 + gq * 4 + r, NN - 1);
        #pragma unroll
        for (int c = 0; c < 8; ++c) {
            const float hv = h[(size_t)nd * 128 + c * 16 + li];
            const float tv = hv + gelu_exact(acc[c][r] + bias[c]);
            acc[c][r] = tv;
            s[r] += tv;
            q[r] += tv * tv;
        }
    }
    #pragma unroll
    for (int off = 1; off < 16; off <<= 1)
        #pragma unroll
        for (int r = 0; r < 4; ++r) {
            s[r] += __shfl_xor(s[r], off);
            q[r] += __shfl_xor(q[r], off);
        }
    #pragma unroll
    for (int r = 0; r < 4; ++r) {
        const int node = node0 + w * 16 + gq * 4 + r;
        if (node >= NN) continue;
        const float mean = s[r] * (1.0f / HID);
        const float var  = q[r] * (1.0f / HID) - mean * mean;
        const float rstd = rsqrtf(var + LN_EPS);
        #pragma unroll
        for (int c = 0; c < 8; ++c) {
            const float y = (acc[c][r] - mean) * rstd * gam[c] + bet[c];
            h[(size_t)node * 128 + c * 16 + li] = y;
            hb[(size_t)node * 128 + c * 16 + li] = f2bf(y);
        }
    }
}

extern "C" void kernel_launch(void* const* d_in, const int* in_sizes, int n_in,
                              void* d_out, int out_size, void* d_ws, size_t ws_size,
                              hipStream_t stream) {
    const float* node_feat = (const float*)d_in[0];
    const float* topo      = (const float*)d_in[1];
    const float* embed     = (const float*)d_in[2];
    const float* W_in      = (const float*)d_in[3];
    const float* b_in      = (const float*)d_in[4];
    const float* ln0_g     = (const float*)d_in[5];
    const float* ln0_b     = (const float*)d_in[6];
    const float* Wl        = (const float*)d_in[7];
    const float* bl        = (const float*)d_in[8];
    const float* Wr        = (const float*)d_in[9];
    const float* ln_g      = (const float*)d_in[10];
    const float* ln_b      = (const float*)d_in[11];
    const int*   opcode    = (const int*)d_in[12];
    const int*   edge      = (const int*)d_in[13];
    const int*   e_src = edge;
    const int*   e_tgt = edge + NE;

    float* h = (float*)d_out;   // 100000 x 128 f32

    char* w = (char*)d_ws;
    ushort* hb     = (ushort*)w;  w += (size_t)NN * HID * sizeof(ushort);   // 25.6 MB
    ushort* aggb   = (ushort*)w;  w += (size_t)NN * HID * sizeof(ushort);   // 25.6 MB
    float* inv_deg = (float*)w;   w += 400016;
    int*   deg_i   = (int*)w;     w += 400016;
    int*   offs    = (int*)w;     w += 400016;    // NN+1 ints
    int*   cursor  = (int*)w;     w += 400016;
    int*   bsum    = (int*)w;     w += 1024;
    int*   boff    = (int*)w;     w += 1024;
    int*   csr     = (int*)w;     w += (size_t)NE * sizeof(int);            // 6.4 MB
    ushort* winp   = (ushort*)w;  w += 7 * 8 * 64 * 8 * sizeof(ushort);     // 57 KB
    ushort* wcat   = (ushort*)w;  w += 4 * 8 * 8 * 64 * 8 * sizeof(ushort); // 262 KB

    // weight packing (input_proj/layer depend on it)
    pack_weights_kernel<<<78, 256, 0, stream>>>(W_in, Wl, Wr, winp, wcat);

    // input projection
    input_proj_mfma<<<(NN + 63) / 64, 256, 0, stream>>>(
        node_feat, topo, embed, opcode, winp, b_in, ln0_g, ln0_b, h, hb);

    // CSR build
    hipMemsetAsync(deg_i, 0, (size_t)NN * sizeof(int), stream);
    degree_int_kernel<<<(NE + 255) / 256, 256, 0, stream>>>(e_tgt, deg_i);
    deg_reduce_kernel<<<SCAN_NBLK, 1024, 0, stream>>>(deg_i, bsum);
    bsum_scan_kernel<<<1, 128, 0, stream>>>(bsum, boff, offs);
    scan_apply_kernel<<<SCAN_NBLK, 1024, 0, stream>>>(deg_i, boff, offs, cursor, inv_deg);
    fill_csr_kernel<<<(NE + 255) / 256, 256, 0, stream>>>(e_src, e_tgt, cursor, csr);

    for (int layer = 0; layer < 4; ++layer) {
        gather_kernel<<<NN / 4, 256, 0, stream>>>(hb, csr, offs, inv_deg, aggb);
        layer_mfma<<<(NN + 63) / 64, 256, 0, stream>>>(
            h, hb, aggb, wcat + (size_t)layer * 8 * 8 * 64 * 8,
            bl + (size_t)layer * HID,
            ln_g + (size_t)layer * HID, ln_b + (size_t)layer * HID);
    }
}

// Round 5
// 712.956 us; speedup vs baseline: 16.1162x; 1.4925x over previous
//
#include <hip/hip_runtime.h>
#include <cstdint>
#include <cstddef>

#define NN 100000
#define NE 1600000
#define FEAT 140
#define EMB 64
#define HID 128
#define LN_EPS 1e-5f
#define SCAN_NBLK 98   // ceil(NN/1024)

typedef unsigned int uint;
typedef unsigned short ushort;
using short8 = __attribute__((ext_vector_type(8))) short;
using f32x4  = __attribute__((ext_vector_type(4))) float;

__device__ __forceinline__ float gelu_exact(float x) {
    return 0.5f * x * (1.0f + erff(x * 0.70710678118654752440f));
}

__device__ __forceinline__ ushort f2bf(float f) {
    uint u = __float_as_uint(f);
    uint r = (u + 0x7fff + ((u >> 16) & 1)) >> 16;
    return (ushort)r;
}

__device__ __forceinline__ float bf2f(ushort u) {
    return __uint_as_float(((uint)u) << 16);
}

__device__ __forceinline__ float bflo(uint u) {
    return __uint_as_float(u << 16);
}
__device__ __forceinline__ float bfhi(uint u) {
    return __uint_as_float(u & 0xffff0000u);
}

// ================= weight packing into MFMA B-fragment order =================
// frag layout per (kk, c): lane l holds 8 bf16, k = kk*32 + (l>>4)*8 + j, col = c*16 + (l&15)
// winp: [7][8][64][8]  (K=224 padded, cols k>=205 zero)
// wcat: [4 layers][8][8][64][8]  (K=256 = [Wl rows 0..127 ; Wr rows 0..127])
__global__ __launch_bounds__(256) void pack_weights_kernel(
    const float* __restrict__ W_in, const float* __restrict__ Wl,
    const float* __restrict__ Wr,
    ushort* __restrict__ winp, ushort* __restrict__ wcat)
{
    const int tid = blockIdx.x * 256 + threadIdx.x;
    const int NIN = 7 * 8 * 64;        // 3584
    const int NL  = 8 * 8 * 64;        // 4096
    if (tid < NIN) {
        const int kk = tid >> 9;
        const int c  = (tid >> 6) & 7;
        const int l  = tid & 63;
        const int kbase = kk * 32 + (l >> 4) * 8;
        const int col = c * 16 + (l & 15);
        short8 v;
        #pragma unroll
        for (int j = 0; j < 8; ++j) {
            const int k = kbase + j;
            v[j] = (k < 205) ? (short)f2bf(W_in[k * 128 + col]) : (short)0;
        }
        *(short8*)(winp + (size_t)tid * 8) = v;
    } else if (tid < NIN + 4 * NL) {
        const int t2 = tid - NIN;
        const int layer = t2 >> 12;
        const int r = t2 & (NL - 1);
        const int kk = r >> 9;
        const int c  = (r >> 6) & 7;
        const int l  = r & 63;
        const int kbase = kk * 32 + (l >> 4) * 8;
        const int col = c * 16 + (l & 15);
        short8 v;
        #pragma unroll
        for (int j = 0; j < 8; ++j) {
            const int k = kbase + j;
            const float x = (k < 128)
                ? Wl[(size_t)layer * 16384 + k * 128 + col]
                : Wr[(size_t)layer * 16384 + (k - 128) * 128 + col];
            v[j] = (short)f2bf(x);
        }
        *(short8*)(wcat + (size_t)t2 * 8) = v;
    }
}

// ================= input projection (MFMA): h = gelu(LN(concat @ W_in + b_in)) =================
__global__ __launch_bounds__(256) void input_proj_mfma(
    const float* __restrict__ nf, const float* __restrict__ topo,
    const float* __restrict__ embed, const int* __restrict__ opcode,
    const ushort* __restrict__ Wp, const float* __restrict__ b_in,
    const float* __restrict__ g0, const float* __restrict__ b0,
    float* __restrict__ h_out, ushort* __restrict__ hb_out)
{
    __shared__ ushort xs[64 * 232];
    const int t = threadIdx.x;
    const int node0 = blockIdx.x * 64;

    for (int idx = t; idx < 64 * 35; idx += 256) {
        const int row = idx / 35, c = idx - row * 35;
        const int node = min(node0 + row, NN - 1);
        const float4 v = ((const float4*)nf)[(size_t)node * 35 + c];
        ushort* p = &xs[row * 232 + c * 4];
        p[0] = f2bf(v.x); p[1] = f2bf(v.y); p[2] = f2bf(v.z); p[3] = f2bf(v.w);
    }
    for (int idx = t; idx < 64 * 16; idx += 256) {
        const int row = idx >> 4, c = idx & 15;
        const int node = min(node0 + row, NN - 1);
        int op = opcode[node];
        op = min(max(op, 0), 127);
        const float4 v = ((const float4*)embed)[op * 16 + c];
        ushort* p = &xs[row * 232 + 140 + c * 4];
        p[0] = f2bf(v.x); p[1] = f2bf(v.y); p[2] = f2bf(v.z); p[3] = f2bf(v.w);
    }
    if (t < 64) {
        const int node = min(node0 + t, NN - 1);
        xs[t * 232 + 204] = f2bf(topo[node]);
    }
    for (int idx = t; idx < 64 * 19; idx += 256) {
        const int row = idx / 19, c = 205 + (idx - row * 19);
        xs[row * 232 + c] = 0;
    }
    __syncthreads();

    const int w = t >> 6, l = t & 63;
    const int gq = l >> 4, li = l & 15;

    f32x4 acc[8];
    #pragma unroll
    for (int c = 0; c < 8; ++c) acc[c] = (f32x4){0.f, 0.f, 0.f, 0.f};

    const short8* Bp = (const short8*)Wp;
    for (int kk = 0; kk < 7; ++kk) {
        const short8 a = *(const short8*)&xs[(w * 16 + li) * 232 + kk * 32 + gq * 8];
        #pragma unroll
        for (int c = 0; c < 8; ++c) {
            const short8 b = Bp[(kk * 8 + c) * 64 + l];
            acc[c] = __builtin_amdgcn_mfma_f32_16x16x32_bf16(a, b, acc[c], 0, 0, 0);
        }
    }

    float bias[8], gam[8], bet[8];
    #pragma unroll
    for (int c = 0; c < 8; ++c) {
        bias[c] = b_in[c * 16 + li];
        gam[c]  = g0[c * 16 + li];
        bet[c]  = b0[c * 16 + li];
    }
    float s[4] = {0, 0, 0, 0}, q[4] = {0, 0, 0, 0};
    #pragma unroll
    for (int c = 0; c < 8; ++c)
        #pragma unroll
        for (int r = 0; r < 4; ++r) {
            const float u = acc[c][r] + bias[c];
            acc[c][r] = u;
            s[r] += u;
            q[r] += u * u;
        }
    #pragma unroll
    for (int off = 1; off < 16; off <<= 1)
        #pragma unroll
        for (int r = 0; r < 4; ++r) {
            s[r] += __shfl_xor(s[r], off);
            q[r] += __shfl_xor(q[r], off);
        }
    #pragma unroll
    for (int r = 0; r < 4; ++r) {
        const int node = node0 + w * 16 + gq * 4 + r;
        if (node >= NN) continue;
        const float mean = s[r] * (1.0f / HID);
        const float var  = q[r] * (1.0f / HID) - mean * mean;
        const float rstd = rsqrtf(var + LN_EPS);
        #pragma unroll
        for (int c = 0; c < 8; ++c) {
            const float y = gelu_exact((acc[c][r] - mean) * rstd * gam[c] + bet[c]);
            h_out[(size_t)node * 128 + c * 16 + li] = y;
            hb_out[(size_t)node * 128 + c * 16 + li] = f2bf(y);
        }
    }
}

// ================= CSR build =================
__global__ __launch_bounds__(256) void degree_int_kernel(const int* __restrict__ tgt,
                                                         int* __restrict__ deg) {
    const int e = blockIdx.x * 256 + threadIdx.x;
    if (e < NE) atomicAdd(&deg[tgt[e]], 1);
}

__global__ __launch_bounds__(1024) void deg_reduce_kernel(const int* __restrict__ deg,
                                                          int* __restrict__ bsum) {
    const int i = blockIdx.x * 1024 + threadIdx.x;
    int v = (i < NN) ? deg[i] : 0;
    #pragma unroll
    for (int off = 32; off >= 1; off >>= 1) v += __shfl_down(v, off);
    __shared__ int wsum[16];
    const int lane = threadIdx.x & 63, wid = threadIdx.x >> 6;
    if (lane == 0) wsum[wid] = v;
    __syncthreads();
    if (threadIdx.x < 16) {
        int s = wsum[threadIdx.x];
        #pragma unroll
        for (int off = 8; off >= 1; off >>= 1) s += __shfl_down(s, off, 16);
        if (threadIdx.x == 0) bsum[blockIdx.x] = s;
    }
}

__global__ __launch_bounds__(128) void bsum_scan_kernel(const int* __restrict__ bsum,
                                                        int* __restrict__ boff,
                                                        int* __restrict__ offs) {
    __shared__ int s_[128];
    const int t = threadIdx.x;
    int v = (t < SCAN_NBLK) ? bsum[t] : 0;
    s_[t] = v;
    __syncthreads();
    for (int off = 1; off < 128; off <<= 1) {
        int u = (t >= off) ? s_[t - off] : 0;
        __syncthreads();
        s_[t] += u;
        __syncthreads();
    }
    if (t < SCAN_NBLK) boff[t] = s_[t] - v;
    if (t == 0) offs[NN] = NE;
}

__global__ __launch_bounds__(1024) void scan_apply_kernel(const int* __restrict__ deg,
                                                          const int* __restrict__ boff,
                                                          int* __restrict__ offs,
                                                          int* __restrict__ cursor,
                                                          float* __restrict__ inv_deg) {
    const int i = blockIdx.x * 1024 + threadIdx.x;
    const int lane = threadIdx.x & 63, wid = threadIdx.x >> 6;
    int v = (i < NN) ? deg[i] : 0;
    int x = v;
    #pragma unroll
    for (int off = 1; off < 64; off <<= 1) {
        int y = __shfl_up(x, off);
        if (lane >= off) x += y;
    }
    __shared__ int wsum[16];
    __shared__ int woff[16];
    if (lane == 63) wsum[wid] = x;
    __syncthreads();
    if (threadIdx.x < 16) {
        const int own = wsum[threadIdx.x];
        int s = own;
        #pragma unroll
        for (int off = 1; off < 16; off <<= 1) {
            int y = __shfl_up(s, off, 16);
            if (threadIdx.x >= off) s += y;
        }
        woff[threadIdx.x] = s - own;
    }
    __syncthreads();
    if (i < NN) {
        const int ex = (x - v) + woff[wid] + boff[blockIdx.x];
        offs[i] = ex;
        cursor[i] = ex;
        inv_deg[i] = 1.0f / fmaxf((float)v, 1.0f);
    }
}

__global__ __launch_bounds__(256) void fill_csr_kernel(const int* __restrict__ src,
                                                       const int* __restrict__ tgt,
                                                       int* __restrict__ cursor,
                                                       int* __restrict__ csr) {
    const int e = blockIdx.x * 256 + threadIdx.x;
    if (e < NE) {
        const int pos = atomicAdd(&cursor[tgt[e]], 1);
        csr[pos] = src[e];
    }
}

// ================= gather: aggb[n] = bf16( inv_deg[n] * sum hb[src] ) =================
// one 64-lane wave per node, uint (2 bf16) per lane; 8-deep unroll for MLP
__global__ __launch_bounds__(256) void gather_kernel(const ushort* __restrict__ hb,
                                                     const int* __restrict__ csr,
                                                     const int* __restrict__ offs,
                                                     const float* __restrict__ inv_deg,
                                                     ushort* __restrict__ aggb) {
    const int node = blockIdx.x * 4 + (threadIdx.x >> 6);
    const int lane = threadIdx.x & 63;
    if (node >= NN) return;
    const int beg = offs[node];
    const int end = offs[node + 1];
    const uint* hp = (const uint*)hb;
    float ax = 0.0f, ay = 0.0f;
    int j = beg;
    for (; j + 8 <= end; j += 8) {
        int s0 = csr[j + 0], s1 = csr[j + 1], s2 = csr[j + 2], s3 = csr[j + 3];
        int s4 = csr[j + 4], s5 = csr[j + 5], s6 = csr[j + 6], s7 = csr[j + 7];
        uint u0 = hp[(size_t)s0 * 64 + lane];
        uint u1 = hp[(size_t)s1 * 64 + lane];
        uint u2 = hp[(size_t)s2 * 64 + lane];
        uint u3 = hp[(size_t)s3 * 64 + lane];
        uint u4 = hp[(size_t)s4 * 64 + lane];
        uint u5 = hp[(size_t)s5 * 64 + lane];
        uint u6 = hp[(size_t)s6 * 64 + lane];
        uint u7 = hp[(size_t)s7 * 64 + lane];
        float ax0 = bflo(u0) + bflo(u1);
        float ax1 = bflo(u2) + bflo(u3);
        float ax2 = bflo(u4) + bflo(u5);
        float ax3 = bflo(u6) + bflo(u7);
        float ay0 = bfhi(u0) + bfhi(u1);
        float ay1 = bfhi(u2) + bfhi(u3);
        float ay2 = bfhi(u4) + bfhi(u5);
        float ay3 = bfhi(u6) + bfhi(u7);
        ax += (ax0 + ax1) + (ax2 + ax3);
        ay += (ay0 + ay1) + (ay2 + ay3);
    }
    for (; j + 2 <= end; j += 2) {
        int s0 = csr[j + 0], s1 = csr[j + 1];
        uint u0 = hp[(size_t)s0 * 64 + lane];
        uint u1 = hp[(size_t)s1 * 64 + lane];
        ax += bflo(u0) + bflo(u1);
        ay += bfhi(u0) + bfhi(u1);
    }
    if (j < end) {
        uint u0 = hp[(size_t)csr[j] * 64 + lane];
        ax += bflo(u0);
        ay += bfhi(u0);
    }
    const float id = inv_deg[node];
    const uint lo = f2bf(ax * id);
    const uint hi = f2bf(ay * id);
    ((uint*)aggb)[(size_t)node * 64 + lane] = lo | (hi << 16);
}

// ================= fused layer (MFMA): h = LN(h + gelu([agg|h] @ [Wl;Wr] + bl)) =================
__global__ __launch_bounds__(256) void layer_mfma(
    float* __restrict__ h, ushort* __restrict__ hb,
    const ushort* __restrict__ aggb, const ushort* __restrict__ Wp,
    const float* __restrict__ bl,
    const float* __restrict__ g, const float* __restrict__ b)
{
    const int t = threadIdx.x;
    const int w = t >> 6, l = t & 63;
    const int gq = l >> 4, li = l & 15;
    const int node0 = blockIdx.x * 64;
    const int ar = min(node0 + w * 16 + li, NN - 1);

    f32x4 acc[8];
    #pragma unroll
    for (int c = 0; c < 8; ++c) acc[c] = (f32x4){0.f, 0.f, 0.f, 0.f};

    const short8* Bp = (const short8*)Wp;
    const short8* Ag = (const short8*)aggb;
    const short8* Hg = (const short8*)hb;
    #pragma unroll
    for (int kk = 0; kk < 8; ++kk) {
        const short8 a = (kk < 4) ? Ag[(size_t)ar * 16 + kk * 4 + gq]
                                  : Hg[(size_t)ar * 16 + (kk - 4) * 4 + gq];
        #pragma unroll
        for (int c = 0; c < 8; ++c) {
            const short8 bf = Bp[(kk * 8 + c) * 64 + l];
            acc[c] = __builtin_amdgcn_mfma_f32_16x16x32_bf16(a, bf, acc[c], 0, 0, 0);
        }
    }

    float bias[8], gam[8], bet[8];
    #pragma unroll
    for (int c = 0; c < 8; ++c) {
        bias[c] = bl[c * 16 + li];
        gam[c]  = g[c * 16 + li];
        bet[c]  = b[c * 16 + li];
    }
    float s[4] = {0, 0, 0, 0}, q[4] = {0, 0, 0, 0};
    #pragma unroll
    for (int r = 0; r < 4; ++r) {
        const int nd = min(node0 + w * 16 + gq * 4 + r, NN - 1);
        #pragma unroll
        for (int c = 0; c < 8; ++c) {
            const float hv = h[(size_t)nd * 128 + c * 16 + li];
            const float tv = hv + gelu_exact(acc[c][r] + bias[c]);
            acc[c][r] = tv;
            s[r] += tv;
            q[r] += tv * tv;
        }
    }
    #pragma unroll
    for (int off = 1; off < 16; off <<= 1)
        #pragma unroll
        for (int r = 0; r < 4; ++r) {
            s[r] += __shfl_xor(s[r], off);
            q[r] += __shfl_xor(q[r], off);
        }
    #pragma unroll
    for (int r = 0; r < 4; ++r) {
        const int node = node0 + w * 16 + gq * 4 + r;
        if (node >= NN) continue;
        const float mean = s[r] * (1.0f / HID);
        const float var  = q[r] * (1.0f / HID) - mean * mean;
        const float rstd = rsqrtf(var + LN_EPS);
        #pragma unroll
        for (int c = 0; c < 8; ++c) {
            const float y = (acc[c][r] - mean) * rstd * gam[c] + bet[c];
            h[(size_t)node * 128 + c * 16 + li] = y;
            hb[(size_t)node * 128 + c * 16 + li] = f2bf(y);
        }
    }
}

extern "C" void kernel_launch(void* const* d_in, const int* in_sizes, int n_in,
                              void* d_out, int out_size, void* d_ws, size_t ws_size,
                              hipStream_t stream) {
    const float* node_feat = (const float*)d_in[0];
    const float* topo      = (const float*)d_in[1];
    const float* embed     = (const float*)d_in[2];
    const float* W_in      = (const float*)d_in[3];
    const float* b_in      = (const float*)d_in[4];
    const float* ln0_g     = (const float*)d_in[5];
    const float* ln0_b     = (const float*)d_in[6];
    const float* Wl        = (const float*)d_in[7];
    const float* bl        = (const float*)d_in[8];
    const float* Wr        = (const float*)d_in[9];
    const float* ln_g      = (const float*)d_in[10];
    const float* ln_b      = (const float*)d_in[11];
    const int*   opcode    = (const int*)d_in[12];
    const int*   edge      = (const int*)d_in[13];
    const int*   e_src = edge;
    const int*   e_tgt = edge + NE;

    float* h = (float*)d_out;   // 100000 x 128 f32

    char* w = (char*)d_ws;
    ushort* hb     = (ushort*)w;  w += (size_t)NN * HID * sizeof(ushort);   // 25.6 MB
    ushort* aggb   = (ushort*)w;  w += (size_t)NN * HID * sizeof(ushort);   // 25.6 MB
    float* inv_deg = (float*)w;   w += 400016;
    int*   deg_i   = (int*)w;     w += 400016;
    int*   offs    = (int*)w;     w += 400016;    // NN+1 ints
    int*   cursor  = (int*)w;     w += 400016;
    int*   bsum    = (int*)w;     w += 1024;
    int*   boff    = (int*)w;     w += 1024;
    int*   csr     = (int*)w;     w += (size_t)NE * sizeof(int);            // 6.4 MB
    ushort* winp   = (ushort*)w;  w += 7 * 8 * 64 * 8 * sizeof(ushort);     // 57 KB
    ushort* wcat   = (ushort*)w;  w += 4 * 8 * 8 * 64 * 8 * sizeof(ushort); // 262 KB

    pack_weights_kernel<<<78, 256, 0, stream>>>(W_in, Wl, Wr, winp, wcat);

    input_proj_mfma<<<(NN + 63) / 64, 256, 0, stream>>>(
        node_feat, topo, embed, opcode, winp, b_in, ln0_g, ln0_b, h, hb);

    hipMemsetAsync(deg_i, 0, (size_t)NN * sizeof(int), stream);
    degree_int_kernel<<<(NE + 255) / 256, 256, 0, stream>>>(e_tgt, deg_i);
    deg_reduce_kernel<<<SCAN_NBLK, 1024, 0, stream>>>(deg_i, bsum);
    bsum_scan_kernel<<<1, 128, 0, stream>>>(bsum, boff, offs);
    scan_apply_kernel<<<SCAN_NBLK, 1024, 0, stream>>>(deg_i, boff, offs, cursor, inv_deg);
    fill_csr_kernel<<<(NE + 255) / 256, 256, 0, stream>>>(e_src, e_tgt, cursor, csr);

    for (int layer = 0; layer < 4; ++layer) {
        gather_kernel<<<NN / 4, 256, 0, stream>>>(hb, csr, offs, inv_deg, aggb);
        layer_mfma<<<(NN + 63) / 64, 256, 0, stream>>>(
            h, hb, aggb, wcat + (size_t)layer * 8 * 8 * 64 * 8,
            bl + (size_t)layer * HID,
            ln_g + (size_t)layer * HID, ln_b + (size_t)layer * HID);
    }
}